// Round 7
// baseline (80.594 us; speedup 1.0000x reference)
//
#include <hip/hip_runtime.h>
#include <hip/hip_bf16.h>

#define CDIM   64
#define HWDIM  4096
#define NCODES 1024
#define NELEM  8388608   // 32*64*64*64 = N*C
#define NBLOCK 512       // vq_main grid: 131072 rows / 256 rows-per-block
#define NPART  2048      // NBLOCK * 4 waves

typedef short bf16x8 __attribute__((ext_vector_type(8)));
typedef float f32x4  __attribute__((ext_vector_type(4)));

__device__ __forceinline__ unsigned short f2bf(float f) {
    union { float f; unsigned u; } v; v.f = f;
    unsigned r = v.u + 0x7fffu + ((v.u >> 16) & 1u);   // round-to-nearest-even
    return (unsigned short)(r >> 16);
}
__device__ __forceinline__ unsigned asu(float f) {
    union { float f; unsigned u; } v; v.f = f; return v.u;
}
__device__ __forceinline__ float asf(unsigned u) {
    union { unsigned u; float f; } v; v.u = u; return v.f;
}

// Precompute bf16 codebook + (-0.5*||e_k||^2) bias (MFMA C-operand).
__global__ void vq_prep(const float* __restrict__ E,
                        unsigned short* __restrict__ Eb,
                        float* __restrict__ bias05) {
    int t = blockIdx.x * blockDim.x + threadIdx.x;   // one thread per code
    if (t < NCODES) {
        float s = 0.f;
        #pragma unroll 8
        for (int c = 0; c < CDIM; ++c) {
            float v = E[t * CDIM + c];
            Eb[t * CDIM + c] = f2bf(v);
            s = fmaf(v, v, s);
        }
        bias05[t] = -0.5f * s;
    }
}

// Block = 4 waves x 64 rows = 256 rows. Codebook staged through LDS in four
// 256-code stages (32 KB buffer -> 4 blocks/CU, 4 waves/SIMD). Swizzled
// layout (16B chunk slot ^= row&7) keeps stride-128B ds_read_b128 conflict-
// minimal. Depth-2 register pipeline (static A/B slots) on the LDS reads.
// score = z.e - 0.5||e||^2 (bias in MFMA C-init); argmax over packed keys.
__global__ __launch_bounds__(256, 4)
void vq_main(const float* __restrict__ z,
             const float* __restrict__ E,
             const unsigned short* __restrict__ Eb,
             const float* __restrict__ bias05,
             float* __restrict__ out,
             float* __restrict__ partial) {
    __shared__ unsigned short sEb[256 * CDIM];   // 32 KB, swizzled

    const int lane = threadIdx.x & 63;
    const int wave = threadIdx.x >> 6;   // 0..3
    const int lrow = lane & 15;          // row/code-col within 16-tile
    const int lgrp = lane >> 4;          // k-group 0..3

    const int n0 = blockIdx.x * 256 + wave * 64;  // wave's first flat row
    const int b  = n0 >> 12;
    const int hw = n0 & 4095;            // 64-aligned; +63 stays in batch
    const float* zb   = z   + (size_t)b * (CDIM * HWDIM);
    float*       outb = out + (size_t)b * (CDIM * HWDIM);

    // A fragments: tile t rows n0+16t..+15. lane holds A[lrow][k=32s+8g+j].
    float szz = 0.f;
    bf16x8 afrag[4][2];
    #pragma unroll
    for (int t = 0; t < 4; ++t)
        #pragma unroll
        for (int s = 0; s < 2; ++s)
            #pragma unroll
            for (int j = 0; j < 8; ++j) {
                int c = 32 * s + 8 * lgrp + j;
                float v = zb[c * HWDIM + hw + t * 16 + lrow];
                szz = fmaf(v, v, szz);
                afrag[t][s][j] = (short)f2bf(v);
            }

    // running packed keys (score with code idx in low 10 bits), argmax
    float run[4][4];
    #pragma unroll
    for (int t = 0; t < 4; ++t)
        #pragma unroll
        for (int r = 0; r < 4; ++r) run[t][r] = -3.0e38f;

    auto ldsB = [&](int rowh, bf16x8& o0, bf16x8& o1) {
        const char* base = (const char*)sEb + rowh * 128;
        const int s0 = (lgrp ^ (rowh & 7)) << 4;
        o0 = *(const bf16x8*)(base + s0);
        o1 = *(const bf16x8*)(base + (s0 ^ 64));
    };
    auto compute = [&](bf16x8 b0, bf16x8 b1, float bv, unsigned code) {
        f32x4 ci = {bv, bv, bv, bv};
        #pragma unroll
        for (int t = 0; t < 4; ++t) {
            f32x4 acc = __builtin_amdgcn_mfma_f32_16x16x32_bf16(afrag[t][0], b0, ci, 0, 0, 0);
            acc = __builtin_amdgcn_mfma_f32_16x16x32_bf16(afrag[t][1], b1, acc, 0, 0, 0);
            #pragma unroll
            for (int r = 0; r < 4; ++r) {
                float key = asf((asu(acc[r]) & 0xFFFFFC00u) | code); // v_and_or_b32
                run[t][r] = fmaxf(run[t][r], key);
            }
        }
    };

    for (int st = 0; st < 4; ++st) {
        // ---- stage 256 codes (32 KB) into LDS, swizzled ----
        if (st) __syncthreads();   // all waves done reading previous stage
        {
            const unsigned short* src = Eb + st * 256 * CDIM;
            #pragma unroll
            for (int i = 0; i < 8; ++i) {
                int cid = i * 256 + threadIdx.x;   // 16B chunk id, 0..2047
                int row = cid >> 3;
                int s   = cid & 7;                 // swizzled slot
                int c   = s ^ (row & 7);           // source chunk
                bf16x8 v = *(const bf16x8*)(src + row * CDIM + c * 8);
                *(bf16x8*)((char*)sEb + row * 128 + s * 16) = v;
            }
        }
        __syncthreads();

        const int cb = st * 256;
        // depth-2 register pipeline over the 16 kt-steps of this stage
        bf16x8 bA0, bA1, bB0, bB1;
        float  bvA, bvB;
        ldsB(lrow,      bA0, bA1);  bvA = bias05[cb + lrow];
        ldsB(16 + lrow, bB0, bB1);  bvB = bias05[cb + 16 + lrow];

        for (int kt = 0; kt < 16; kt += 2) {
            {   // even step (row kt*16+lrow)
                bf16x8 t0 = bA0, t1 = bA1; float tv = bvA;
                int nr = ((kt + 2) * 16 + lrow) & 255;   // wrap in-stage
                ldsB(nr, bA0, bA1);
                bvA = bias05[cb + nr];
                compute(t0, t1, tv, (unsigned)(cb + kt * 16 + lrow));
            }
            {   // odd step (row (kt+1)*16+lrow)
                bf16x8 t0 = bB0, t1 = bB1; float tv = bvB;
                int nr = ((kt + 3) * 16 + lrow) & 255;
                ldsB(nr, bB0, bB1);
                bvB = bias05[cb + nr];
                compute(t0, t1, tv, (unsigned)(cb + (kt + 1) * 16 + lrow));
            }
        }
    }

    // reduce packed keys across the 16 code-columns (lrow lanes): pure max
    #pragma unroll
    for (int m = 1; m <= 8; m <<= 1)
        #pragma unroll
        for (int t = 0; t < 4; ++t)
            #pragma unroll
            for (int r = 0; r < 4; ++r)
                run[t][r] = fmaxf(run[t][r], __shfl_xor(run[t][r], m, 64));

    // redistribute winners via shuffles: lane (lrow,lgrp) holds rows 4g+r;
    // epilogue thread needs row lrow of each tile.
    int idxe[4];
    #pragma unroll
    for (int t = 0; t < 4; ++t) {
        const int src = (lrow >> 2) << 4;   // a lane whose lgrp == lrow>>2
        float g0 = __shfl(run[t][0], src, 64);
        float g1 = __shfl(run[t][1], src, 64);
        float g2 = __shfl(run[t][2], src, 64);
        float g3 = __shfl(run[t][3], src, 64);
        float sel = (lrow & 2) ? ((lrow & 1) ? g3 : g2)
                               : ((lrow & 1) ? g1 : g0);
        idxe[t] = (int)(asu(sel) & 1023u);
    }

    // epilogue: gather fp32 codebook rows, write transposed out
    #pragma unroll
    for (int t = 0; t < 4; ++t) {
        const int idxr = idxe[t];
        const f32x4* ep  = (const f32x4*)(E + idxr * CDIM      + 8 * lgrp);
        const f32x4* ep2 = (const f32x4*)(E + idxr * CDIM + 32 + 8 * lgrp);
        f32x4 qa = ep[0], qb = ep[1], qc = ep2[0], qd = ep2[1];
        float* ob = outb + hw + t * 16 + lrow;
        #pragma unroll
        for (int j = 0; j < 4; ++j) {
            ob[(8 * lgrp + j)          * HWDIM] = qa[j];
            ob[(8 * lgrp + 4 + j)      * HWDIM] = qb[j];
            ob[(32 + 8 * lgrp + j)     * HWDIM] = qc[j];
            ob[(32 + 8 * lgrp + 4 + j) * HWDIM] = qd[j];
        }
    }

    // loss partial: sum z^2 + sum over rows of d_min (= -2 * packed score)
    float dsum = 0.f;
    #pragma unroll
    for (int t = 0; t < 4; ++t)
        #pragma unroll
        for (int r = 0; r < 4; ++r) dsum += run[t][r];
    float contrib = szz + ((lrow == 0) ? (-2.f * dsum) : 0.f);
    #pragma unroll
    for (int m = 32; m >= 1; m >>= 1) contrib += __shfl_xor(contrib, m, 64);
    if (lane == 0) partial[blockIdx.x * 4 + wave] = contrib;
}

__global__ void vq_fin(const float* __restrict__ partial,
                       float* __restrict__ out) {
    int lane = threadIdx.x;   // 64 threads
    float s = 0.f;
    for (int i = lane; i < NPART; i += 64) s += partial[i];
    #pragma unroll
    for (int m = 32; m >= 1; m >>= 1) s += __shfl_xor(s, m, 64);
    if (lane == 0) out[NELEM] = 1.25f * s / (float)NELEM;
}

extern "C" void kernel_launch(void* const* d_in, const int* in_sizes, int n_in,
                              void* d_out, int out_size, void* d_ws, size_t ws_size,
                              hipStream_t stream) {
    const float* z = (const float*)d_in[0];
    const float* E = (const float*)d_in[1];
    float* out = (float*)d_out;

    unsigned short* Eb = (unsigned short*)d_ws;                    // 128 KB
    float* bias05      = (float*)((char*)d_ws + 131072);           // 4 KB
    float* partial     = (float*)((char*)d_ws + 131072 + 4096);    // 8 KB

    vq_prep<<<4, 256, 0, stream>>>(E, Eb, bias05);
    vq_main<<<NBLOCK, 256, 0, stream>>>(z, E, Eb, bias05, out, partial);
    vq_fin<<<1, 64, 0, stream>>>(partial, out);
}

// Round 8
// 63.354 us; speedup vs baseline: 1.2721x; 1.2721x over previous
//
#include <hip/hip_runtime.h>
#include <hip/hip_bf16.h>

#define CDIM   64
#define HWDIM  4096
#define NCODES 1024
#define NELEM  8388608   // 32*64*64*64 = N*C
#define NBLOCK 1024      // vq_main grid: 131072 rows / 128 rows-per-block
#define NPART  4096      // NBLOCK * 4 waves

typedef short bf16x8 __attribute__((ext_vector_type(8)));
typedef float f32x4  __attribute__((ext_vector_type(4)));

__device__ __forceinline__ unsigned short f2bf(float f) {
    union { float f; unsigned u; } v; v.f = f;
    unsigned r = v.u + 0x7fffu + ((v.u >> 16) & 1u);   // round-to-nearest-even
    return (unsigned short)(r >> 16);
}
__device__ __forceinline__ unsigned asu(float f) {
    union { float f; unsigned u; } v; v.f = f; return v.u;
}
__device__ __forceinline__ float asf(unsigned u) {
    union { unsigned u; float f; } v; v.u = u; return v.f;
}

// Precompute bf16 codebook + (-0.5*||e_k||^2) bias (MFMA C-operand).
__global__ void vq_prep(const float* __restrict__ E,
                        unsigned short* __restrict__ Eb,
                        float* __restrict__ bias05) {
    int t = blockIdx.x * blockDim.x + threadIdx.x;   // one thread per code
    if (t < NCODES) {
        float s = 0.f;
        #pragma unroll 8
        for (int c = 0; c < CDIM; ++c) {
            float v = E[t * CDIM + c];
            Eb[t * CDIM + c] = f2bf(v);
            s = fmaf(v, v, s);
        }
        bias05[t] = -0.5f * s;
    }
}

// Block = 4 waves x 32 rows = 128 rows; grid 1024 so 4-5 blocks/CU are
// resident (R6 was grid-capped at 2). Codebook staged through LDS in four
// 256-code stages (32 KB, swizzled: 16B chunk slot ^= row&7). Depth-2
// register pipeline on the LDS B-reads. score = z.e - 0.5||e||^2 (bias in
// MFMA C-init); argmax over packed keys (code idx in low 10 mantissa bits).
// NOTE: no min-waves clamp — R7's __launch_bounds__(256,4) forced VGPR=64
// and spilled the pipeline to scratch (FETCH/WRITE doubled).
__global__ __launch_bounds__(256)
void vq_main(const float* __restrict__ z,
             const float* __restrict__ E,
             const unsigned short* __restrict__ Eb,
             const float* __restrict__ bias05,
             float* __restrict__ out,
             float* __restrict__ partial) {
    __shared__ unsigned short sEb[256 * CDIM];   // 32 KB, swizzled

    const int lane = threadIdx.x & 63;
    const int wave = threadIdx.x >> 6;   // 0..3
    const int lrow = lane & 15;          // row/code-col within 16-tile
    const int lgrp = lane >> 4;          // k-group 0..3

    const int n0 = blockIdx.x * 128 + wave * 32;  // wave's first flat row
    const int b  = n0 >> 12;
    const int hw = n0 & 4095;            // 32-aligned; +31 stays in batch
    const float* zb   = z   + (size_t)b * (CDIM * HWDIM);
    float*       outb = out + (size_t)b * (CDIM * HWDIM);

    // A fragments: tile t rows n0+16t..+15. lane holds A[lrow][k=32s+8g+j].
    float szz = 0.f;
    bf16x8 afrag[2][2];
    #pragma unroll
    for (int t = 0; t < 2; ++t)
        #pragma unroll
        for (int s = 0; s < 2; ++s)
            #pragma unroll
            for (int j = 0; j < 8; ++j) {
                int c = 32 * s + 8 * lgrp + j;
                float v = zb[c * HWDIM + hw + t * 16 + lrow];
                szz = fmaf(v, v, szz);
                afrag[t][s][j] = (short)f2bf(v);
            }

    // running packed keys (score with code idx in low 10 bits), argmax
    float run[2][4];
    #pragma unroll
    for (int t = 0; t < 2; ++t)
        #pragma unroll
        for (int r = 0; r < 4; ++r) run[t][r] = -3.0e38f;

    auto ldsB = [&](int rowh, bf16x8& o0, bf16x8& o1) {
        const char* base = (const char*)sEb + rowh * 128;
        const int s0 = (lgrp ^ (rowh & 7)) << 4;
        o0 = *(const bf16x8*)(base + s0);
        o1 = *(const bf16x8*)(base + (s0 ^ 64));
    };
    auto compute = [&](bf16x8 b0, bf16x8 b1, float bv, unsigned code) {
        f32x4 ci = {bv, bv, bv, bv};
        #pragma unroll
        for (int t = 0; t < 2; ++t) {
            f32x4 acc = __builtin_amdgcn_mfma_f32_16x16x32_bf16(afrag[t][0], b0, ci, 0, 0, 0);
            acc = __builtin_amdgcn_mfma_f32_16x16x32_bf16(afrag[t][1], b1, acc, 0, 0, 0);
            #pragma unroll
            for (int r = 0; r < 4; ++r) {
                float key = asf((asu(acc[r]) & 0xFFFFFC00u) | code); // v_and_or_b32
                run[t][r] = fmaxf(run[t][r], key);
            }
        }
    };

    for (int st = 0; st < 4; ++st) {
        // ---- stage 256 codes (32 KB) into LDS, swizzled ----
        if (st) __syncthreads();   // all waves done reading previous stage
        {
            const unsigned short* src = Eb + st * 256 * CDIM;
            #pragma unroll
            for (int i = 0; i < 8; ++i) {
                int cid = i * 256 + threadIdx.x;   // 16B chunk id, 0..2047
                int row = cid >> 3;
                int s   = cid & 7;                 // swizzled slot
                int c   = s ^ (row & 7);           // source chunk
                bf16x8 v = *(const bf16x8*)(src + row * CDIM + c * 8);
                *(bf16x8*)((char*)sEb + row * 128 + s * 16) = v;
            }
        }
        __syncthreads();

        const int cb = st * 256;
        // depth-2 register pipeline over the 16 kt-steps of this stage
        bf16x8 bA0, bA1, bB0, bB1;
        float  bvA, bvB;
        ldsB(lrow,      bA0, bA1);  bvA = bias05[cb + lrow];
        ldsB(16 + lrow, bB0, bB1);  bvB = bias05[cb + 16 + lrow];

        for (int kt = 0; kt < 16; kt += 2) {
            {   // even step (row kt*16+lrow)
                bf16x8 t0 = bA0, t1 = bA1; float tv = bvA;
                int nr = ((kt + 2) * 16 + lrow) & 255;   // wrap in-stage
                ldsB(nr, bA0, bA1);
                bvA = bias05[cb + nr];
                compute(t0, t1, tv, (unsigned)(cb + kt * 16 + lrow));
            }
            {   // odd step (row (kt+1)*16+lrow)
                bf16x8 t0 = bB0, t1 = bB1; float tv = bvB;
                int nr = ((kt + 3) * 16 + lrow) & 255;
                ldsB(nr, bB0, bB1);
                bvB = bias05[cb + nr];
                compute(t0, t1, tv, (unsigned)(cb + (kt + 1) * 16 + lrow));
            }
        }
    }

    // reduce packed keys across the 16 code-columns (lrow lanes): pure max
    #pragma unroll
    for (int m = 1; m <= 8; m <<= 1)
        #pragma unroll
        for (int t = 0; t < 2; ++t)
            #pragma unroll
            for (int r = 0; r < 4; ++r)
                run[t][r] = fmaxf(run[t][r], __shfl_xor(run[t][r], m, 64));

    // redistribute winners via shuffles: lane (lrow,lgrp) holds rows 4g+r;
    // epilogue thread needs row lrow of each tile.
    int idxe[2];
    #pragma unroll
    for (int t = 0; t < 2; ++t) {
        const int src = (lrow >> 2) << 4;   // a lane whose lgrp == lrow>>2
        float g0 = __shfl(run[t][0], src, 64);
        float g1 = __shfl(run[t][1], src, 64);
        float g2 = __shfl(run[t][2], src, 64);
        float g3 = __shfl(run[t][3], src, 64);
        float sel = (lrow & 2) ? ((lrow & 1) ? g3 : g2)
                               : ((lrow & 1) ? g1 : g0);
        idxe[t] = (int)(asu(sel) & 1023u);
    }

    // epilogue: gather fp32 codebook rows, write transposed out
    #pragma unroll
    for (int t = 0; t < 2; ++t) {
        const int idxr = idxe[t];
        const f32x4* ep  = (const f32x4*)(E + idxr * CDIM      + 8 * lgrp);
        const f32x4* ep2 = (const f32x4*)(E + idxr * CDIM + 32 + 8 * lgrp);
        f32x4 qa = ep[0], qb = ep[1], qc = ep2[0], qd = ep2[1];
        float* ob = outb + hw + t * 16 + lrow;
        #pragma unroll
        for (int j = 0; j < 4; ++j) {
            ob[(8 * lgrp + j)          * HWDIM] = qa[j];
            ob[(8 * lgrp + 4 + j)      * HWDIM] = qb[j];
            ob[(32 + 8 * lgrp + j)     * HWDIM] = qc[j];
            ob[(32 + 8 * lgrp + 4 + j) * HWDIM] = qd[j];
        }
    }

    // loss partial: sum z^2 + sum over rows of d_min (= -2 * packed score)
    float dsum = 0.f;
    #pragma unroll
    for (int t = 0; t < 2; ++t)
        #pragma unroll
        for (int r = 0; r < 4; ++r) dsum += run[t][r];
    float contrib = szz + ((lrow == 0) ? (-2.f * dsum) : 0.f);
    #pragma unroll
    for (int m = 32; m >= 1; m >>= 1) contrib += __shfl_xor(contrib, m, 64);
    if (lane == 0) partial[blockIdx.x * 4 + wave] = contrib;
}

__global__ void vq_fin(const float* __restrict__ partial,
                       float* __restrict__ out) {
    int lane = threadIdx.x;   // 64 threads
    float s = 0.f;
    for (int i = lane; i < NPART; i += 64) s += partial[i];
    #pragma unroll
    for (int m = 32; m >= 1; m >>= 1) s += __shfl_xor(s, m, 64);
    if (lane == 0) out[NELEM] = 1.25f * s / (float)NELEM;
}

extern "C" void kernel_launch(void* const* d_in, const int* in_sizes, int n_in,
                              void* d_out, int out_size, void* d_ws, size_t ws_size,
                              hipStream_t stream) {
    const float* z = (const float*)d_in[0];
    const float* E = (const float*)d_in[1];
    float* out = (float*)d_out;

    unsigned short* Eb = (unsigned short*)d_ws;                    // 128 KB
    float* bias05      = (float*)((char*)d_ws + 131072);           // 4 KB
    float* partial     = (float*)((char*)d_ws + 131072 + 4096);    // 16 KB

    vq_prep<<<4, 256, 0, stream>>>(E, Eb, bias05);
    vq_main<<<NBLOCK, 256, 0, stream>>>(z, E, Eb, bias05, out, partial);
    vq_fin<<<1, 64, 0, stream>>>(partial, out);
}

// Round 9
// 59.126 us; speedup vs baseline: 1.3631x; 1.0715x over previous
//
#include <hip/hip_runtime.h>
#include <hip/hip_bf16.h>

#define CDIM   64
#define HWDIM  4096
#define NCODES 1024
#define NELEM  8388608   // 32*64*64*64 = N*C
#define NBLOCK 1024      // vq_main grid: 131072 rows / 128 rows-per-block
#define NPART  4096      // NBLOCK * 4 waves

typedef short bf16x8 __attribute__((ext_vector_type(8)));
typedef float f32x4  __attribute__((ext_vector_type(4)));

__device__ __forceinline__ unsigned short f2bf(float f) {
    union { float f; unsigned u; } v; v.f = f;
    unsigned r = v.u + 0x7fffu + ((v.u >> 16) & 1u);   // round-to-nearest-even
    return (unsigned short)(r >> 16);
}
__device__ __forceinline__ unsigned asu(float f) {
    union { float f; unsigned u; } v; v.f = f; return v.u;
}
__device__ __forceinline__ float asf(unsigned u) {
    union { unsigned u; float f; } v; v.u = u; return v.f;
}
__device__ __forceinline__ void gload_lds16(const void* g, void* l) {
    __builtin_amdgcn_global_load_lds(
        (const __attribute__((address_space(1))) void*)g,
        (__attribute__((address_space(3))) void*)l, 16, 0, 0);
}

// Precompute bf16 codebook + (-0.5*||e_k||^2) bias (MFMA C-operand).
__global__ void vq_prep(const float* __restrict__ E,
                        unsigned short* __restrict__ Eb,
                        float* __restrict__ bias05) {
    int t = blockIdx.x * blockDim.x + threadIdx.x;   // one thread per code
    if (t < NCODES) {
        float s = 0.f;
        #pragma unroll 8
        for (int c = 0; c < CDIM; ++c) {
            float v = E[t * CDIM + c];
            Eb[t * CDIM + c] = f2bf(v);
            s = fmaf(v, v, s);
        }
        bias05[t] = -0.5f * s;
    }
}

// Block = 4 waves x 32 rows = 128 rows; grid 1024 (4 blocks/CU at 36 KB LDS).
// Codebook staged via async global_load_lds (16B, linear LDS dest + inverse-
// swizzled per-lane global src) into a double-buffered pair of 128-code
// stages; bias05 staged into LDS once. The K-loop touches ONLY LDS.
// score = z.e - 0.5||e||^2 (bias in MFMA C-init); argmax over packed keys
// (code idx in low 10 mantissa bits -> v_and_or + v_max).
__global__ __launch_bounds__(256)
void vq_main(const float* __restrict__ z,
             const float* __restrict__ E,
             const unsigned short* __restrict__ Eb,
             const float* __restrict__ bias05,
             float* __restrict__ out,
             float* __restrict__ partial) {
    __shared__ unsigned short sEb[2][128 * CDIM];   // 2 x 16 KB, swizzled
    __shared__ float sBias[NCODES];                 // 4 KB

    const int lane = threadIdx.x & 63;
    const int wave = threadIdx.x >> 6;   // 0..3
    const int lrow = lane & 15;          // row/code-col within 16-tile
    const int lgrp = lane >> 4;          // k-group 0..3

    const int n0 = blockIdx.x * 128 + wave * 32;  // wave's first flat row
    const int b  = n0 >> 12;
    const int hw = n0 & 4095;            // 32-aligned; +31 stays in batch
    const float* zb   = z   + (size_t)b * (CDIM * HWDIM);
    float*       outb = out + (size_t)b * (CDIM * HWDIM);

    // issue async staging of stage 0 into buffer 0 + bias into LDS
    auto issue_stage = [&](int st, int bufi) {
        const unsigned short* src = Eb + st * 128 * CDIM;
        #pragma unroll
        for (int i = 0; i < 4; ++i) {
            const int c   = wave * 256 + i * 64 + lane;  // 16B chunk 0..1023
            const int row = c >> 3;
            const int s   = c & 7;
            // linear LDS dest (wave-uniform base + lane*16), inverse-swizzled
            // global source: LDS slot s receives source chunk s^(row&7).
            const unsigned short* g = src + row * CDIM + ((s ^ (row & 7)) << 3);
            unsigned short* l = &sEb[bufi][(wave * 256 + i * 64) * 8];
            gload_lds16(g, l);
        }
    };
    ((float4*)sBias)[threadIdx.x] = ((const float4*)bias05)[threadIdx.x];
    issue_stage(0, 0);

    // A fragments: tile t rows n0+16t..+15. lane holds A[lrow][k=32s+8g+j].
    float szz = 0.f;
    bf16x8 afrag[2][2];
    #pragma unroll
    for (int t = 0; t < 2; ++t)
        #pragma unroll
        for (int s = 0; s < 2; ++s)
            #pragma unroll
            for (int j = 0; j < 8; ++j) {
                int c = 32 * s + 8 * lgrp + j;
                float v = zb[c * HWDIM + hw + t * 16 + lrow];
                szz = fmaf(v, v, szz);
                afrag[t][s][j] = (short)f2bf(v);
            }

    // running packed keys (score with code idx in low 10 bits), argmax
    float run[2][4];
    #pragma unroll
    for (int t = 0; t < 2; ++t)
        #pragma unroll
        for (int r = 0; r < 4; ++r) run[t][r] = -3.0e38f;

    auto ldsB = [&](int bufi, int rowh, bf16x8& o0, bf16x8& o1) {
        const char* base = (const char*)&sEb[bufi][0] + rowh * 128;
        const int s0 = (lgrp ^ (rowh & 7)) << 4;
        o0 = *(const bf16x8*)(base + s0);
        o1 = *(const bf16x8*)(base + (s0 ^ 64));
    };
    auto compute = [&](bf16x8 b0, bf16x8 b1, float bv, unsigned code) {
        f32x4 ci = {bv, bv, bv, bv};
        #pragma unroll
        for (int t = 0; t < 2; ++t) {
            f32x4 acc = __builtin_amdgcn_mfma_f32_16x16x32_bf16(afrag[t][0], b0, ci, 0, 0, 0);
            acc = __builtin_amdgcn_mfma_f32_16x16x32_bf16(afrag[t][1], b1, acc, 0, 0, 0);
            #pragma unroll
            for (int r = 0; r < 4; ++r) {
                float key = asf((asu(acc[r]) & 0xFFFFFC00u) | code); // v_and_or_b32
                run[t][r] = fmaxf(run[t][r], key);
            }
        }
    };

    __syncthreads();   // bias + stage-0 DMA complete (vmcnt/lgkm drain)

    for (int st = 0; st < 8; ++st) {
        // issue next stage's DMA into the other buffer (safe: the barrier
        // ending stage st-1 guarantees all waves finished reading it)
        if (st < 7) issue_stage(st + 1, (st + 1) & 1);

        const int bufi = st & 1;
        const int cb   = st * 128;
        // depth-2 register pipeline over the 8 kt-steps of this stage
        bf16x8 bA0, bA1, bB0, bB1;
        float  bvA, bvB;
        ldsB(bufi, lrow,      bA0, bA1);  bvA = sBias[cb + lrow];
        ldsB(bufi, 16 + lrow, bB0, bB1);  bvB = sBias[cb + 16 + lrow];

        for (int kt = 0; kt < 8; kt += 2) {
            {   // even step (stage row kt*16+lrow)
                bf16x8 t0 = bA0, t1 = bA1; float tv = bvA;
                int nr = ((kt + 2) * 16 + lrow) & 127;   // wrap in-stage
                ldsB(bufi, nr, bA0, bA1);
                bvA = sBias[cb + nr];
                compute(t0, t1, tv, (unsigned)(cb + kt * 16 + lrow));
            }
            {   // odd step (stage row (kt+1)*16+lrow)
                bf16x8 t0 = bB0, t1 = bB1; float tv = bvB;
                int nr = ((kt + 3) * 16 + lrow) & 127;
                ldsB(bufi, nr, bB0, bB1);
                bvB = sBias[cb + nr];
                compute(t0, t1, tv, (unsigned)(cb + (kt + 1) * 16 + lrow));
            }
        }
        // barrier: separates reads of buf[st&1] from stage st+2's DMA AND
        // drains vmcnt so stage st+1's DMA is complete before it's read.
        if (st < 7) __syncthreads();
    }

    // reduce packed keys across the 16 code-columns (lrow lanes): pure max
    #pragma unroll
    for (int m = 1; m <= 8; m <<= 1)
        #pragma unroll
        for (int t = 0; t < 2; ++t)
            #pragma unroll
            for (int r = 0; r < 4; ++r)
                run[t][r] = fmaxf(run[t][r], __shfl_xor(run[t][r], m, 64));

    // redistribute winners via shuffles: lane (lrow,lgrp) holds rows 4g+r;
    // epilogue thread needs row lrow of each tile.
    int idxe[2];
    #pragma unroll
    for (int t = 0; t < 2; ++t) {
        const int src = (lrow >> 2) << 4;   // a lane whose lgrp == lrow>>2
        float g0 = __shfl(run[t][0], src, 64);
        float g1 = __shfl(run[t][1], src, 64);
        float g2 = __shfl(run[t][2], src, 64);
        float g3 = __shfl(run[t][3], src, 64);
        float sel = (lrow & 2) ? ((lrow & 1) ? g3 : g2)
                               : ((lrow & 1) ? g1 : g0);
        idxe[t] = (int)(asu(sel) & 1023u);
    }

    // epilogue: gather fp32 codebook rows, write transposed out
    #pragma unroll
    for (int t = 0; t < 2; ++t) {
        const int idxr = idxe[t];
        const f32x4* ep  = (const f32x4*)(E + idxr * CDIM      + 8 * lgrp);
        const f32x4* ep2 = (const f32x4*)(E + idxr * CDIM + 32 + 8 * lgrp);
        f32x4 qa = ep[0], qb = ep[1], qc = ep2[0], qd = ep2[1];
        float* ob = outb + hw + t * 16 + lrow;
        #pragma unroll
        for (int j = 0; j < 4; ++j) {
            ob[(8 * lgrp + j)          * HWDIM] = qa[j];
            ob[(8 * lgrp + 4 + j)      * HWDIM] = qb[j];
            ob[(32 + 8 * lgrp + j)     * HWDIM] = qc[j];
            ob[(32 + 8 * lgrp + 4 + j) * HWDIM] = qd[j];
        }
    }

    // loss partial: sum z^2 + sum over rows of d_min (= -2 * packed score)
    float dsum = 0.f;
    #pragma unroll
    for (int t = 0; t < 2; ++t)
        #pragma unroll
        for (int r = 0; r < 4; ++r) dsum += run[t][r];
    float contrib = szz + ((lrow == 0) ? (-2.f * dsum) : 0.f);
    #pragma unroll
    for (int m = 32; m >= 1; m >>= 1) contrib += __shfl_xor(contrib, m, 64);
    if (lane == 0) partial[blockIdx.x * 4 + wave] = contrib;
}

__global__ void vq_fin(const float* __restrict__ partial,
                       float* __restrict__ out) {
    int lane = threadIdx.x;   // 64 threads
    float s = 0.f;
    for (int i = lane; i < NPART; i += 64) s += partial[i];
    #pragma unroll
    for (int m = 32; m >= 1; m >>= 1) s += __shfl_xor(s, m, 64);
    if (lane == 0) out[NELEM] = 1.25f * s / (float)NELEM;
}

extern "C" void kernel_launch(void* const* d_in, const int* in_sizes, int n_in,
                              void* d_out, int out_size, void* d_ws, size_t ws_size,
                              hipStream_t stream) {
    const float* z = (const float*)d_in[0];
    const float* E = (const float*)d_in[1];
    float* out = (float*)d_out;

    unsigned short* Eb = (unsigned short*)d_ws;                    // 128 KB
    float* bias05      = (float*)((char*)d_ws + 131072);           // 4 KB
    float* partial     = (float*)((char*)d_ws + 131072 + 4096);    // 16 KB

    vq_prep<<<4, 256, 0, stream>>>(E, Eb, bias05);
    vq_main<<<NBLOCK, 256, 0, stream>>>(z, E, Eb, bias05, out, partial);
    vq_fin<<<1, 64, 0, stream>>>(partial, out);
}

// Round 10
// 56.070 us; speedup vs baseline: 1.4374x; 1.0545x over previous
//
#include <hip/hip_runtime.h>
#include <hip/hip_bf16.h>

#define CDIM   64
#define HWDIM  4096
#define NCODES 1024
#define NELEM  8388608   // 32*64*64*64 = N*C
#define NBLOCK 256       // vq_main grid: one block per CU
#define NPART  4096      // NBLOCK * 16 waves
#define LDSSZ  (NCODES * CDIM * 2 + NCODES * 4)   // 128 KB codebook + 4 KB bias

typedef short bf16x8 __attribute__((ext_vector_type(8)));
typedef float f32x4  __attribute__((ext_vector_type(4)));

__device__ __forceinline__ unsigned short f2bf(float f) {
    union { float f; unsigned u; } v; v.f = f;
    unsigned r = v.u + 0x7fffu + ((v.u >> 16) & 1u);   // round-to-nearest-even
    return (unsigned short)(r >> 16);
}
__device__ __forceinline__ unsigned asu(float f) {
    union { float f; unsigned u; } v; v.f = f; return v.u;
}
__device__ __forceinline__ float asf(unsigned u) {
    union { unsigned u; float f; } v; v.u = u; return v.f;
}
__device__ __forceinline__ void gload_lds16(const void* g, void* l) {
    __builtin_amdgcn_global_load_lds(
        (const __attribute__((address_space(1))) void*)g,
        (__attribute__((address_space(3))) void*)l, 16, 0, 0);
}

// Precompute bf16 codebook + (-0.5*||e_k||^2) bias (MFMA C-operand).
__global__ void vq_prep(const float* __restrict__ E,
                        unsigned short* __restrict__ Eb,
                        float* __restrict__ bias05) {
    int t = blockIdx.x * blockDim.x + threadIdx.x;   // one thread per code
    if (t < NCODES) {
        float s = 0.f;
        #pragma unroll 8
        for (int c = 0; c < CDIM; ++c) {
            float v = E[t * CDIM + c];
            Eb[t * CDIM + c] = f2bf(v);
            s = fmaf(v, v, s);
        }
        bias05[t] = -0.5f * s;
    }
}

// One block per CU: 1024 threads = 16 waves, FULL codebook (128 KB, swizzled)
// + bias (4 KB) in dynamic LDS, staged once via async global_load_lds.
// ONE barrier total; afterwards each wave independently processes its 32 rows
// (A-load -> 64-step LDS-only K-loop -> epilogue). Wave desync overlaps the
// HBM/LDS/MFMA/VALU phases that previous rounds ran in barrier-convoyed
// lockstep. score = z.e - 0.5||e||^2; argmax over packed keys (code idx in
// low 10 mantissa bits -> v_and_or + v_max).
__global__ __launch_bounds__(1024)
void vq_main(const float* __restrict__ z,
             const float* __restrict__ E,
             const unsigned short* __restrict__ Eb,
             const float* __restrict__ bias05,
             float* __restrict__ out,
             float* __restrict__ partial) {
    extern __shared__ char smem[];
    unsigned short* sEb = (unsigned short*)smem;           // 128 KB swizzled
    float* sBias = (float*)(smem + NCODES * CDIM * 2);     // 4 KB

    const int lane = threadIdx.x & 63;
    const int wave = threadIdx.x >> 6;   // 0..15
    const int lrow = lane & 15;          // row/code-col within 16-tile
    const int lgrp = lane >> 4;          // k-group 0..3

    const int n0 = blockIdx.x * 512 + wave * 32;  // wave's first flat row
    const int b  = n0 >> 12;
    const int hw = n0 & 4095;            // 32-aligned; +31 stays in batch
    const float* zb   = z   + (size_t)b * (CDIM * HWDIM);
    float*       outb = out + (size_t)b * (CDIM * HWDIM);

    // ---- stage the full codebook via async DMA (linear LDS dest, inverse-
    // swizzled per-lane global source: LDS chunk s of row gets source chunk
    // s^(row&7)), plus bias. 8192 chunks of 16 B = 128 KB.
    #pragma unroll
    for (int i = 0; i < 8; ++i) {
        const int c   = i * 1024 + wave * 64 + lane;   // chunk id 0..8191
        const int row = c >> 3;
        const int s   = c & 7;
        const unsigned short* g = Eb + row * CDIM + ((s ^ (row & 7)) << 3);
        gload_lds16(g, &sEb[(i * 1024 + wave * 64) * 8]);
    }
    if (threadIdx.x < 256) ((float4*)sBias)[threadIdx.x] = ((const float4*)bias05)[threadIdx.x];

    // A fragments: tile t rows n0+16t..+15. lane holds A[lrow][k=32s+8g+j].
    float szz = 0.f;
    bf16x8 afrag[2][2];
    #pragma unroll
    for (int t = 0; t < 2; ++t)
        #pragma unroll
        for (int s = 0; s < 2; ++s)
            #pragma unroll
            for (int j = 0; j < 8; ++j) {
                int c = 32 * s + 8 * lgrp + j;
                float v = zb[c * HWDIM + hw + t * 16 + lrow];
                szz = fmaf(v, v, szz);
                afrag[t][s][j] = (short)f2bf(v);
            }

    // running packed keys (score with code idx in low 10 bits), argmax
    float run[2][4];
    #pragma unroll
    for (int t = 0; t < 2; ++t)
        #pragma unroll
        for (int r = 0; r < 4; ++r) run[t][r] = -3.0e38f;

    auto ldsB = [&](int rowh, bf16x8& o0, bf16x8& o1) {
        const char* base = (const char*)sEb + rowh * 128;
        const int s0 = (lgrp ^ (rowh & 7)) << 4;
        o0 = *(const bf16x8*)(base + s0);
        o1 = *(const bf16x8*)(base + (s0 ^ 64));
    };
    auto compute = [&](bf16x8 b0, bf16x8 b1, float bv, unsigned code) {
        f32x4 ci = {bv, bv, bv, bv};
        #pragma unroll
        for (int t = 0; t < 2; ++t) {
            f32x4 acc = __builtin_amdgcn_mfma_f32_16x16x32_bf16(afrag[t][0], b0, ci, 0, 0, 0);
            acc = __builtin_amdgcn_mfma_f32_16x16x32_bf16(afrag[t][1], b1, acc, 0, 0, 0);
            #pragma unroll
            for (int r = 0; r < 4; ++r) {
                float key = asf((asu(acc[r]) & 0xFFFFFC00u) | code); // v_and_or_b32
                run[t][r] = fmaxf(run[t][r], key);
            }
        }
    };

    __syncthreads();   // the ONLY barrier: DMA + bias complete

    // depth-2 register pipeline over all 64 kt-steps (LDS-only accesses)
    {
        bf16x8 bA0, bA1, bB0, bB1;
        float  bvA, bvB;
        ldsB(lrow,      bA0, bA1);  bvA = sBias[lrow];
        ldsB(16 + lrow, bB0, bB1);  bvB = sBias[16 + lrow];

        for (int kt = 0; kt < 64; kt += 2) {
            {   // even step (row kt*16+lrow)
                bf16x8 t0 = bA0, t1 = bA1; float tv = bvA;
                int nr = ((kt + 2) * 16 + lrow) & 1023;   // wrap
                ldsB(nr, bA0, bA1);
                bvA = sBias[nr];
                compute(t0, t1, tv, (unsigned)(kt * 16 + lrow));
            }
            {   // odd step (row (kt+1)*16+lrow)
                bf16x8 t0 = bB0, t1 = bB1; float tv = bvB;
                int nr = ((kt + 3) * 16 + lrow) & 1023;
                ldsB(nr, bB0, bB1);
                bvB = sBias[nr];
                compute(t0, t1, tv, (unsigned)((kt + 1) * 16 + lrow));
            }
        }
    }

    // reduce packed keys across the 16 code-columns (lrow lanes): pure max
    #pragma unroll
    for (int m = 1; m <= 8; m <<= 1)
        #pragma unroll
        for (int t = 0; t < 2; ++t)
            #pragma unroll
            for (int r = 0; r < 4; ++r)
                run[t][r] = fmaxf(run[t][r], __shfl_xor(run[t][r], m, 64));

    // redistribute winners via shuffles: lane (lrow,lgrp) holds rows 4g+r;
    // epilogue thread needs row lrow of each tile.
    int idxe[2];
    #pragma unroll
    for (int t = 0; t < 2; ++t) {
        const int src = (lrow >> 2) << 4;   // a lane whose lgrp == lrow>>2
        float g0 = __shfl(run[t][0], src, 64);
        float g1 = __shfl(run[t][1], src, 64);
        float g2 = __shfl(run[t][2], src, 64);
        float g3 = __shfl(run[t][3], src, 64);
        float sel = (lrow & 2) ? ((lrow & 1) ? g3 : g2)
                               : ((lrow & 1) ? g1 : g0);
        idxe[t] = (int)(asu(sel) & 1023u);
    }

    // epilogue: gather fp32 codebook rows, write transposed out
    #pragma unroll
    for (int t = 0; t < 2; ++t) {
        const int idxr = idxe[t];
        const f32x4* ep  = (const f32x4*)(E + idxr * CDIM      + 8 * lgrp);
        const f32x4* ep2 = (const f32x4*)(E + idxr * CDIM + 32 + 8 * lgrp);
        f32x4 qa = ep[0], qb = ep[1], qc = ep2[0], qd = ep2[1];
        float* ob = outb + hw + t * 16 + lrow;
        #pragma unroll
        for (int j = 0; j < 4; ++j) {
            ob[(8 * lgrp + j)          * HWDIM] = qa[j];
            ob[(8 * lgrp + 4 + j)      * HWDIM] = qb[j];
            ob[(32 + 8 * lgrp + j)     * HWDIM] = qc[j];
            ob[(32 + 8 * lgrp + 4 + j) * HWDIM] = qd[j];
        }
    }

    // loss partial: sum z^2 + sum over rows of d_min (= -2 * packed score)
    float dsum = 0.f;
    #pragma unroll
    for (int t = 0; t < 2; ++t)
        #pragma unroll
        for (int r = 0; r < 4; ++r) dsum += run[t][r];
    float contrib = szz + ((lrow == 0) ? (-2.f * dsum) : 0.f);
    #pragma unroll
    for (int m = 32; m >= 1; m >>= 1) contrib += __shfl_xor(contrib, m, 64);
    if (lane == 0) partial[blockIdx.x * 16 + wave] = contrib;
}

__global__ void vq_fin(const float* __restrict__ partial,
                       float* __restrict__ out) {
    int lane = threadIdx.x;   // 64 threads
    float s = 0.f;
    for (int i = lane; i < NPART; i += 64) s += partial[i];
    #pragma unroll
    for (int m = 32; m >= 1; m >>= 1) s += __shfl_xor(s, m, 64);
    if (lane == 0) out[NELEM] = 1.25f * s / (float)NELEM;
}

extern "C" void kernel_launch(void* const* d_in, const int* in_sizes, int n_in,
                              void* d_out, int out_size, void* d_ws, size_t ws_size,
                              hipStream_t stream) {
    const float* z = (const float*)d_in[0];
    const float* E = (const float*)d_in[1];
    float* out = (float*)d_out;

    unsigned short* Eb = (unsigned short*)d_ws;                    // 128 KB
    float* bias05      = (float*)((char*)d_ws + 131072);           // 4 KB
    float* partial     = (float*)((char*)d_ws + 131072 + 4096);    // 16 KB

    // allow >64 KB dynamic LDS (host-side attribute set; deterministic,
    // not a stream operation -> graph-capture safe)
    hipFuncSetAttribute((const void*)vq_main,
                        hipFuncAttributeMaxDynamicSharedMemorySize, LDSSZ);

    vq_prep<<<4, 256, 0, stream>>>(E, Eb, bias05);
    vq_main<<<NBLOCK, 1024, LDSSZ, stream>>>(z, E, Eb, bias05, out, partial);
    vq_fin<<<1, 64, 0, stream>>>(partial, out);
}

// Round 11
// 51.656 us; speedup vs baseline: 1.5602x; 1.0855x over previous
//
#include <hip/hip_runtime.h>
#include <hip/hip_bf16.h>

#define CDIM   64
#define HWDIM  4096
#define NCODES 1024
#define NELEM  8388608   // 32*64*64*64 = N*C
#define NBLOCK 256       // vq_main grid: one block per CU
#define NPART  4096      // NBLOCK * 16 waves
#define LDSSZ  (131072 + 16 * 68 * 4)   // 128 KB codebook + padded bias

typedef short bf16x8 __attribute__((ext_vector_type(8)));
typedef float f32x4  __attribute__((ext_vector_type(4)));

__device__ __forceinline__ unsigned short f2bf(float f) {
    union { float f; unsigned u; } v; v.f = f;
    unsigned r = v.u + 0x7fffu + ((v.u >> 16) & 1u);   // round-to-nearest-even
    return (unsigned short)(r >> 16);
}
__device__ __forceinline__ unsigned asu(float f) {
    union { float f; unsigned u; } v; v.f = f; return v.u;
}
__device__ __forceinline__ float asf(unsigned u) {
    union { unsigned u; float f; } v; v.u = u; return v.f;
}
__device__ __forceinline__ void gload_lds16(const void* g, void* l) {
    __builtin_amdgcn_global_load_lds(
        (const __attribute__((address_space(1))) void*)g,
        (__attribute__((address_space(3))) void*)l, 16, 0, 0);
}

// Precompute bf16 codebook + (-0.5*||e_k||^2) bias (MFMA C-operand).
__global__ void vq_prep(const float* __restrict__ E,
                        unsigned short* __restrict__ Eb,
                        float* __restrict__ bias05) {
    int t = blockIdx.x * blockDim.x + threadIdx.x;   // one thread per code
    if (t < NCODES) {
        float s = 0.f;
        #pragma unroll 8
        for (int c = 0; c < CDIM; ++c) {
            float v = E[t * CDIM + c];
            Eb[t * CDIM + c] = f2bf(v);
            s = fmaf(v, v, s);
        }
        bias05[t] = -0.5f * s;
    }
}

// One block per CU (1024 thr = 16 waves), full codebook (128 KB swizzled) +
// transposed bias in dynamic LDS, staged once via async global_load_lds; one
// barrier; then each wave independently scans its 32 rows x 1024 codes.
// K-loop addressing is fully hoisted: swizzled B-frag address is loop-
// invariant (rowh&7 == lrow&7 since kt*16 = 0 mod 8), so reads are
// ds_read_b128 [pA/pB + immediate j*2048]; bias comes 8-per-chunk via two
// ds_read_b128 from sBiasT[lrow][kt] (pad 68 -> 2-way conflicts only).
// score = z.e - 0.5||e||^2 (bias in MFMA C-init); argmax over packed keys
// (code idx in low 10 mantissa bits -> v_and_or + v_max).
__global__ __launch_bounds__(1024)
void vq_main(const float* __restrict__ z,
             const float* __restrict__ E,
             const unsigned short* __restrict__ Eb,
             const float* __restrict__ bias05,
             float* __restrict__ out,
             float* __restrict__ partial) {
    extern __shared__ char smem[];
    unsigned short* sEb = (unsigned short*)smem;           // 128 KB swizzled
    float (*sBiasT)[68] = (float(*)[68])(smem + 131072);   // [16][68] padded

    const int lane = threadIdx.x & 63;
    const int wave = threadIdx.x >> 6;   // 0..15
    const int lrow = lane & 15;          // row/code-col within 16-tile
    const int lgrp = lane >> 4;          // k-group 0..3

    const int n0 = blockIdx.x * 512 + wave * 32;  // wave's first flat row
    const int b  = n0 >> 12;
    const int hw = n0 & 4095;            // 32-aligned; +31 stays in batch
    const float* zb   = z   + (size_t)b * (CDIM * HWDIM);
    float*       outb = out + (size_t)b * (CDIM * HWDIM);

    // ---- stage full codebook via async DMA (linear LDS dest, inverse-
    // swizzled per-lane global source: LDS chunk s of row holds source chunk
    // s^(row&7)). 8192 chunks of 16 B = 128 KB.
    #pragma unroll
    for (int i = 0; i < 8; ++i) {
        const int c   = i * 1024 + wave * 64 + lane;   // chunk id 0..8191
        const int row = c >> 3;
        const int s   = c & 7;
        const unsigned short* g = Eb + row * CDIM + ((s ^ (row & 7)) << 3);
        gload_lds16(g, &sEb[(i * 1024 + wave * 64) * 8]);
    }
    // bias, transposed: sBiasT[code&15][code>>4]
    {
        const int i = threadIdx.x;
        sBiasT[i & 15][i >> 4] = bias05[i];
    }

    // A fragments: tile t rows n0+16t..+15. lane holds A[lrow][k=32s+8g+j].
    float szz = 0.f;
    bf16x8 afrag[2][2];
    #pragma unroll
    for (int t = 0; t < 2; ++t)
        #pragma unroll
        for (int s = 0; s < 2; ++s)
            #pragma unroll
            for (int j = 0; j < 8; ++j) {
                int c = 32 * s + 8 * lgrp + j;
                float v = zb[c * HWDIM + hw + t * 16 + lrow];
                szz = fmaf(v, v, szz);
                afrag[t][s][j] = (short)f2bf(v);
            }

    float run[2][4];
    #pragma unroll
    for (int t = 0; t < 2; ++t)
        #pragma unroll
        for (int r = 0; r < 4; ++r) run[t][r] = -3.0e38f;

    __syncthreads();   // the ONLY barrier: DMA + bias complete

    // loop-invariant swizzled addresses (rowh&7 == lrow&7 for all kt)
    const int s0byte = (lgrp ^ (lrow & 7)) << 4;
    const char* pa = (const char*)sEb + lrow * 128 + s0byte;
    const char* pb = (const char*)sEb + lrow * 128 + (s0byte ^ 64);
    const float* pbias = &sBiasT[lrow][0];
    unsigned codev = (unsigned)lrow;

    for (int ch = 0; ch < 8; ++ch) {
        f32x4 bq0 = *(const f32x4*)(pbias);       // biases kt = ch*8+0..3
        f32x4 bq1 = *(const f32x4*)(pbias + 4);   // biases kt = ch*8+4..7
        #pragma unroll
        for (int j = 0; j < 8; ++j) {
            bf16x8 b0 = *(const bf16x8*)(pa + j * 2048);
            bf16x8 b1 = *(const bf16x8*)(pb + j * 2048);
            const float bv = (j < 4) ? bq0[j] : bq1[j - 4];   // static idx
            f32x4 ci = {bv, bv, bv, bv};
            f32x4 a0 = __builtin_amdgcn_mfma_f32_16x16x32_bf16(afrag[0][0], b0, ci, 0, 0, 0);
            a0 = __builtin_amdgcn_mfma_f32_16x16x32_bf16(afrag[0][1], b1, a0, 0, 0, 0);
            f32x4 a1 = __builtin_amdgcn_mfma_f32_16x16x32_bf16(afrag[1][0], b0, ci, 0, 0, 0);
            a1 = __builtin_amdgcn_mfma_f32_16x16x32_bf16(afrag[1][1], b1, a1, 0, 0, 0);
            const unsigned code = codev + (unsigned)(j * 16);
            #pragma unroll
            for (int r = 0; r < 4; ++r) {
                float k0 = asf((asu(a0[r]) & 0xFFFFFC00u) | code);
                run[0][r] = fmaxf(run[0][r], k0);
                float k1 = asf((asu(a1[r]) & 0xFFFFFC00u) | code);
                run[1][r] = fmaxf(run[1][r], k1);
            }
        }
        pa += 16384; pb += 16384; pbias += 8; codev += 128;
    }

    // reduce packed keys across the 16 code-columns (lrow lanes): pure max
    #pragma unroll
    for (int m = 1; m <= 8; m <<= 1)
        #pragma unroll
        for (int t = 0; t < 2; ++t)
            #pragma unroll
            for (int r = 0; r < 4; ++r)
                run[t][r] = fmaxf(run[t][r], __shfl_xor(run[t][r], m, 64));

    // redistribute winners via shuffles: lane (lrow,lgrp) holds rows 4g+r;
    // epilogue thread needs row lrow of each tile.
    int idxe[2];
    #pragma unroll
    for (int t = 0; t < 2; ++t) {
        const int src = (lrow >> 2) << 4;   // a lane whose lgrp == lrow>>2
        float g0 = __shfl(run[t][0], src, 64);
        float g1 = __shfl(run[t][1], src, 64);
        float g2 = __shfl(run[t][2], src, 64);
        float g3 = __shfl(run[t][3], src, 64);
        float sel = (lrow & 2) ? ((lrow & 1) ? g3 : g2)
                               : ((lrow & 1) ? g1 : g0);
        idxe[t] = (int)(asu(sel) & 1023u);
    }

    // epilogue: gather fp32 codebook rows, write transposed out
    #pragma unroll
    for (int t = 0; t < 2; ++t) {
        const int idxr = idxe[t];
        const f32x4* ep  = (const f32x4*)(E + idxr * CDIM      + 8 * lgrp);
        const f32x4* ep2 = (const f32x4*)(E + idxr * CDIM + 32 + 8 * lgrp);
        f32x4 qa = ep[0], qb = ep[1], qc = ep2[0], qd = ep2[1];
        float* ob = outb + hw + t * 16 + lrow;
        #pragma unroll
        for (int j = 0; j < 4; ++j) {
            ob[(8 * lgrp + j)          * HWDIM] = qa[j];
            ob[(8 * lgrp + 4 + j)      * HWDIM] = qb[j];
            ob[(32 + 8 * lgrp + j)     * HWDIM] = qc[j];
            ob[(32 + 8 * lgrp + 4 + j) * HWDIM] = qd[j];
        }
    }

    // loss partial: sum z^2 + sum over rows of d_min (= -2 * packed score)
    float dsum = 0.f;
    #pragma unroll
    for (int t = 0; t < 2; ++t)
        #pragma unroll
        for (int r = 0; r < 4; ++r) dsum += run[t][r];
    float contrib = szz + ((lrow == 0) ? (-2.f * dsum) : 0.f);
    #pragma unroll
    for (int m = 32; m >= 1; m >>= 1) contrib += __shfl_xor(contrib, m, 64);
    if (lane == 0) partial[blockIdx.x * 16 + wave] = contrib;
}

__global__ void vq_fin(const float* __restrict__ partial,
                       float* __restrict__ out) {
    int lane = threadIdx.x;   // 64 threads
    float s = 0.f;
    for (int i = lane; i < NPART; i += 64) s += partial[i];
    #pragma unroll
    for (int m = 32; m >= 1; m >>= 1) s += __shfl_xor(s, m, 64);
    if (lane == 0) out[NELEM] = 1.25f * s / (float)NELEM;
}

extern "C" void kernel_launch(void* const* d_in, const int* in_sizes, int n_in,
                              void* d_out, int out_size, void* d_ws, size_t ws_size,
                              hipStream_t stream) {
    const float* z = (const float*)d_in[0];
    const float* E = (const float*)d_in[1];
    float* out = (float*)d_out;

    unsigned short* Eb = (unsigned short*)d_ws;                    // 128 KB
    float* bias05      = (float*)((char*)d_ws + 131072);           // 4 KB
    float* partial     = (float*)((char*)d_ws + 131072 + 4096);    // 16 KB

    // allow >64 KB dynamic LDS (host-side attribute; graph-capture safe)
    hipFuncSetAttribute((const void*)vq_main,
                        hipFuncAttributeMaxDynamicSharedMemorySize, LDSSZ);

    vq_prep<<<4, 256, 0, stream>>>(E, Eb, bias05);
    vq_main<<<NBLOCK, 1024, LDSSZ, stream>>>(z, E, Eb, bias05, out, partial);
    vq_fin<<<1, 64, 0, stream>>>(partial, out);
}